// Round 15
// baseline (151.341 us; speedup 1.0000x reference)
//
#include <hip/hip_runtime.h>
#include <math.h>

#define NB 8
#define NS 512
#define NE 32
#define DE 256
#define DH 512
#define DA 200
#define DAP 224   // padded att dim (7 tiles of 32)
#define NJ 7

typedef __bf16 bf16x8 __attribute__((ext_vector_type(8)));
typedef float f32x16 __attribute__((ext_vector_type(16)));

__device__ __forceinline__ float tanh_fast(float x) {
    float e = __expf(x + x);
    return fmaf(-2.f, __builtin_amdgcn_rcpf(e + 1.f), 1.f);
}

// ---- stage 1: partial sums of cxt over s-chunks (512 blocks) ----
__global__ __launch_bounds__(256) void cmean_partial(const float* __restrict__ cxt,
                                                     float* __restrict__ psum) {
    const int g = blockIdx.x;       // b*64 + c
    const int b = g >> 6, c = g & 63;
    const int t = threadIdx.x;
    const float* base = cxt + ((size_t)b * NS + c * 8) * DH;
    float s0 = 0.f, s1 = 0.f;
    #pragma unroll
    for (int s = 0; s < 8; ++s) {
        s0 += base[s * DH + t];
        s1 += base[s * DH + t + 256];
    }
    psum[(size_t)g * DH + t]       = s0;
    psum[(size_t)g * DH + t + 256] = s1;
}

// ---- stage 2: reduce partials -> cmean; hatt[b][a] = cmean @ Wh (zero-padded) ----
__global__ __launch_bounds__(256) void hatt_from_psum(const float* __restrict__ psum,
                                                      const float* __restrict__ Wh,
                                                      float* __restrict__ hattw) {
    const int b = blockIdx.x;
    const int t = threadIdx.x;
    __shared__ float cm[DH];
    float s0 = 0.f, s1 = 0.f;
    for (int c = 0; c < 64; ++c) {
        s0 += psum[((size_t)b * 64 + c) * DH + t];
        s1 += psum[((size_t)b * 64 + c) * DH + t + 256];
    }
    cm[t]       = s0 * (1.f / NS);
    cm[t + 256] = s1 * (1.f / NS);
    __syncthreads();
    if (t < DAP) {
        float acc = 0.f;
        if (t < DA)
            for (int h = 0; h < DH; ++h)
                acc = fmaf(cm[h], Wh[h * DA + t], acc);
        hattw[b * DAP + t] = acc;
    }
}

// ---- stage 3: pack We into bf16 B-fragment layout (zero-padded cols) ----
__global__ __launch_bounds__(64) void wef_build(const float* __restrict__ We,
                                                __bf16* __restrict__ wef) {
    const int f = blockIdx.x;
    const int l = threadIdx.x;
    const int nj = f >> 4, kk = f & 15;
    const int n = nj * 32 + (l & 31);
    bf16x8 v;
    #pragma unroll
    for (int e = 0; e < 8; ++e) {
        int K = kk * 16 + ((l >> 5) << 2) + (e & 3) + 8 * (e >> 2);
        v[e] = (__bf16)((n < DA) ? We[K * DA + n] : 0.f);
    }
    reinterpret_cast<bf16x8*>(wef)[f * 64 + l] = v;
}

// ---- main: LINEAR per-wave streaming of ent + LDS-swizzled fragment gather ----
// Round-14 falsified "batch depth"; invariant was the strided A-frag access
// pattern (32x 1KB-strided streams per wave -> ~1.8 TB/s). Here each wave
// loads contiguous 1KB rows (lane-linear), stages to LDS with source-side XOR
// swizzle (linear dest, m173 pattern), and both the MFMA A-frags and the
// epilogue weighted-sum gather from LDS. B-frags (1 nj per wave) live in
// registers; epilogue entirely from LDS (no global re-read). Double-buffered
// 2-tile rounds, next round's loads issued before compute (T14).
__global__ __launch_bounds__(512) void entatt_main(const float* __restrict__ ent,
                                                   const __bf16* __restrict__ wef,
                                                   const float* __restrict__ hattw,
                                                   const float* __restrict__ Ws,
                                                   float* __restrict__ out) {
    const int t    = threadIdx.x;
    const int lane = t & 63;
    const int wid  = t >> 6;            // 0..7
    const int m    = lane & 31;
    const int hi   = lane >> 5;
    const int g    = blockIdx.x;        // 0..255 (16 tiles each)
    const int b    = g >> 5;            // 32 blocks per batch

    __shared__ float buf[2][16384];         // 2 x 64KB: [tile2][row32][256f], swizzled
    __shared__ float partials[2][NJ][NE];   // [tile][nj-wave][entity]

    // ---- B fragments for this wave's nj + att-col scalars (wid<7) ----
    bf16x8 B[16];
    float ha = 0.f, wsa = 0.f;
    if (wid < NJ) {
        const bf16x8* wef8 = reinterpret_cast<const bf16x8*>(wef);
        #pragma unroll
        for (int kk = 0; kk < 16; ++kk) B[kk] = wef8[(wid * 16 + kk) * 64 + lane];
        const int a = wid * 32 + m;
        ha  = hattw[b * DAP + a];
        wsa = (a < DA) ? Ws[a] : 0.f;
    }

    float4 u[8];

    // ---- prologue: stage round 0 into buf[0] ----
    {
        const size_t base = (size_t)(g * 16) * 8192;
        #pragma unroll
        for (int j = 0; j < 8; ++j) {
            const int Rj = wid * 8 + j;          // 0..63 (2 tiles x 32 rows)
            const int mR = Rj & 31;
            const float* src = ent + base + (size_t)(Rj >> 5) * 8192
                             + mR * 256 + ((lane ^ mR) << 2);
            u[j] = *reinterpret_cast<const float4*>(src);
        }
        __builtin_amdgcn_sched_barrier(0);
        float4* d4 = reinterpret_cast<float4*>(buf[0]);
        #pragma unroll
        for (int j = 0; j < 8; ++j) d4[(wid * 8 + j) * 64 + lane] = u[j];
    }
    __syncthreads();

    #pragma unroll 1
    for (int r = 0; r < 8; ++r) {
        const int cur = r & 1;

        // ---- issue next round's loads (in flight across this round's compute) ----
        if (r < 7) {
            const size_t base = (size_t)(g * 16 + (r + 1) * 2) * 8192;
            #pragma unroll
            for (int j = 0; j < 8; ++j) {
                const int Rj = wid * 8 + j;
                const int mR = Rj & 31;
                const float* src = ent + base + (size_t)(Rj >> 5) * 8192
                                 + mR * 256 + ((lane ^ mR) << 2);
                u[j] = *reinterpret_cast<const float4*>(src);
            }
            __builtin_amdgcn_sched_barrier(0);
        }

        // ---- compute both tiles: A-frags gathered from swizzled LDS ----
        if (wid < NJ) {
            #pragma unroll
            for (int tau = 0; tau < 2; ++tau) {
                const float4* bf4 = reinterpret_cast<const float4*>(&buf[cur][tau * 8192]);
                f32x16 acc;
                #pragma unroll
                for (int q = 0; q < 16; ++q) acc[q] = 0.f;
                #pragma unroll
                for (int kk = 0; kk < 16; ++kk) {
                    const int k0 = kk * 4 + hi;   // float4-slot of frag low half
                    float4 p0 = bf4[m * 64 + (k0 ^ m)];
                    float4 p1 = bf4[m * 64 + ((k0 + 2) ^ m)];
                    bf16x8 fr = { (__bf16)p0.x, (__bf16)p0.y, (__bf16)p0.z, (__bf16)p0.w,
                                  (__bf16)p1.x, (__bf16)p1.y, (__bf16)p1.z, (__bf16)p1.w };
                    acc = __builtin_amdgcn_mfma_f32_32x32x16_bf16(fr, B[kk], acc, 0, 0, 0);
                }
                #pragma unroll
                for (int q = 0; q < 16; ++q) {
                    float v = tanh_fast(acc[q] + ha) * wsa;
                    v += __shfl_xor(v, 1);  v += __shfl_xor(v, 2);  v += __shfl_xor(v, 4);
                    v += __shfl_xor(v, 8);  v += __shfl_xor(v, 16);
                    if (m == 0)
                        partials[tau][wid][(q & 3) + 8 * (q >> 2) + 4 * hi] = v;
                }
            }
        }
        __syncthreads();   // partials ready (implicit vmcnt drain ~covered by compute)

        // ---- epilogue: softmax + weighted sum from LDS; 4 waves per tile ----
        {
            const int tau = wid >> 2;
            const int q4  = wid & 3;
            const int e0  = lane & 31;
            float lg = 0.f;
            #pragma unroll
            for (int w = 0; w < NJ; ++w) lg += partials[tau][w][e0];
            float mx = lg;
            mx = fmaxf(mx, __shfl_xor(mx, 1));  mx = fmaxf(mx, __shfl_xor(mx, 2));
            mx = fmaxf(mx, __shfl_xor(mx, 4));  mx = fmaxf(mx, __shfl_xor(mx, 8));
            mx = fmaxf(mx, __shfl_xor(mx, 16));
            float ex = __expf(lg - mx);
            float sm = ex;
            sm += __shfl_xor(sm, 1);  sm += __shfl_xor(sm, 2);  sm += __shfl_xor(sm, 4);
            sm += __shfl_xor(sm, 8);  sm += __shfl_xor(sm, 16);
            const float wv = ex * __builtin_amdgcn_rcpf(sm);
            const float* bt = &buf[cur][tau * 8192];
            const int d = q4 * 64 + lane;
            float o = 0.f;
            #pragma unroll
            for (int e = 0; e < NE; ++e) {
                float we = __shfl(wv, e);
                o = fmaf(we, bt[e * 256 + (d ^ (e << 2))], o);
            }
            out[(size_t)(g * 16 + r * 2 + tau) * 256 + d] = o;
        }

        // ---- write staged rows into the other buffer ----
        if (r < 7) {
            float4* d4 = reinterpret_cast<float4*>(buf[cur ^ 1]);
            #pragma unroll
            for (int j = 0; j < 8; ++j) d4[(wid * 8 + j) * 64 + lane] = u[j];
        }
        __syncthreads();
    }
}

extern "C" void kernel_launch(void* const* d_in, const int* in_sizes, int n_in,
                              void* d_out, int out_size, void* d_ws, size_t ws_size,
                              hipStream_t stream) {
    const float* cxt = (const float*)d_in[0];
    const float* ent = (const float*)d_in[1];
    const float* We  = (const float*)d_in[2];
    const float* Wh  = (const float*)d_in[3];
    const float* Ws  = (const float*)d_in[4];
    float* out = (float*)d_out;

    float*  psum  = (float*)d_ws;                       // 512*512 f32 = 1 MB
    float*  hattw = psum + 512 * DH;                    // 8*224 f32
    __bf16* wef   = (__bf16*)(hattw + NB * DAP);        // 7*16*512 bf16 = 112 KB

    hipLaunchKernelGGL(wef_build, dim3(NJ * 16), dim3(64), 0, stream, We, wef);
    hipLaunchKernelGGL(cmean_partial, dim3(512), dim3(256), 0, stream, cxt, psum);
    hipLaunchKernelGGL(hatt_from_psum, dim3(NB), dim3(256), 0, stream, psum, Wh, hattw);
    hipLaunchKernelGGL(entatt_main, dim3(256), dim3(512), 0, stream,
                       ent, wef, hattw, Ws, out);
}

// Round 17
// 128.844 us; speedup vs baseline: 1.1746x; 1.1746x over previous
//
#include <hip/hip_runtime.h>
#include <math.h>

#define NB 8
#define NS 512
#define NE 32
#define DE 256
#define DH 512
#define DA 200
#define DAP 224   // padded att dim (7 tiles of 32)
#define NJ 7

typedef __bf16 bf16x8 __attribute__((ext_vector_type(8)));
typedef float f32x16 __attribute__((ext_vector_type(16)));

#define GLOBAL_AS __attribute__((address_space(1)))
#define LDS_AS    __attribute__((address_space(3)))

__device__ __forceinline__ float tanh_fast(float x) {
    float e = __expf(x + x);
    return fmaf(-2.f, __builtin_amdgcn_rcpf(e + 1.f), 1.f);
}

// ---- stage 1: partial sums of cxt over s-chunks (512 blocks) ----
__global__ __launch_bounds__(256) void cmean_partial(const float* __restrict__ cxt,
                                                     float* __restrict__ psum) {
    const int g = blockIdx.x;       // b*64 + c
    const int b = g >> 6, c = g & 63;
    const int t = threadIdx.x;
    const float* base = cxt + ((size_t)b * NS + c * 8) * DH;
    float s0 = 0.f, s1 = 0.f;
    #pragma unroll
    for (int s = 0; s < 8; ++s) {
        s0 += base[s * DH + t];
        s1 += base[s * DH + t + 256];
    }
    psum[(size_t)g * DH + t]       = s0;
    psum[(size_t)g * DH + t + 256] = s1;
}

// ---- stage 2: reduce partials -> cmean; hatt[b][a] = cmean @ Wh (zero-padded) ----
__global__ __launch_bounds__(256) void hatt_from_psum(const float* __restrict__ psum,
                                                      const float* __restrict__ Wh,
                                                      float* __restrict__ hattw) {
    const int b = blockIdx.x;
    const int t = threadIdx.x;
    __shared__ float cm[DH];
    float s0 = 0.f, s1 = 0.f;
    for (int c = 0; c < 64; ++c) {
        s0 += psum[((size_t)b * 64 + c) * DH + t];
        s1 += psum[((size_t)b * 64 + c) * DH + t + 256];
    }
    cm[t]       = s0 * (1.f / NS);
    cm[t + 256] = s1 * (1.f / NS);
    __syncthreads();
    if (t < DAP) {
        float acc = 0.f;
        if (t < DA)
            for (int h = 0; h < DH; ++h)
                acc = fmaf(cm[h], Wh[h * DA + t], acc);
        hattw[b * DAP + t] = acc;
    }
}

// ---- stage 3: pack We into bf16 B-fragment layout (zero-padded cols) ----
__global__ __launch_bounds__(64) void wef_build(const float* __restrict__ We,
                                                __bf16* __restrict__ wef) {
    const int f = blockIdx.x;
    const int l = threadIdx.x;
    const int nj = f >> 4, kk = f & 15;
    const int n = nj * 32 + (l & 31);
    bf16x8 v;
    #pragma unroll
    for (int e = 0; e < 8; ++e) {
        int K = kk * 16 + ((l >> 5) << 2) + (e & 3) + 8 * (e >> 2);
        v[e] = (__bf16)((n < DA) ? We[K * DA + n] : 0.f);
    }
    reinterpret_cast<bf16x8*>(wef)[f * 64 + l] = v;
}

// ---- main: global_load_lds staging (no VGPR round-trip), 1 read of ent ----
// ROUND-16 POSTMORTEM: the 0.85 absmax was a GRID bug (256 blocks x 8 tiles
// = 2048 of 4096 tiles; half of out stayed zero). Fixed: 512 blocks.
// Structure: fire-and-forget DMA (rounds 5-15 cap at ~1.8 TB/s on the VGPR
// load path), 2-round double buffer, XOR-swizzled-source staging (linear LDS
// dest, guide #21/m173), swizzled MFMA gather + swizzled LDS epilogue.
__global__ __launch_bounds__(512) void entatt_main(const float* __restrict__ ent,
                                                   const __bf16* __restrict__ wef,
                                                   const float* __restrict__ hattw,
                                                   const float* __restrict__ Ws,
                                                   float* __restrict__ out) {
    const int t    = threadIdx.x;
    const int lane = t & 63;
    const int wid  = t >> 6;            // 0..7
    const int m    = lane & 31;
    const int hi   = lane >> 5;
    const int g    = blockIdx.x;        // 0..511, 8 tiles each
    const int b    = g >> 6;            // 64 blocks per batch

    __shared__ float buf[2][2 * 8192];      // 2 dbuf x 2 tiles x 32KB = 128KB
    __shared__ float partials[2][8][NE];    // [tile][nj-wave][entity]

    // ---- B fragments for this wave's nj + att-col scalars (wid<7) ----
    bf16x8 B[16];
    float ha = 0.f, wsa = 0.f;
    if (wid < NJ) {
        const bf16x8* wef8 = reinterpret_cast<const bf16x8*>(wef);
        #pragma unroll
        for (int kk = 0; kk < 16; ++kk) B[kk] = wef8[(wid * 16 + kk) * 64 + lane];
        const int a = wid * 32 + m;
        ha  = hattw[b * DAP + a];
        wsa = (a < DA) ? Ws[a] : 0.f;
    }

    // ---- stage one round (2 tiles, 64 rows) into buf[nb] via global_load_lds ----
    // wave wid stages rows R = wid*8 + j; swizzle key = j = R&7 = (row&31)&7.
    // lane's 16B source = row start + ((lane ^ j) * 16): LDS slot l holds col4 l^j.
    auto stage = [&](int rr, int nb) {
        const size_t tile0 = (size_t)(g * 8 + rr * 2);
        #pragma unroll
        for (int j = 0; j < 8; ++j) {
            const int R   = wid * 8 + j;        // 0..63
            const int tau = R >> 5, mr = R & 31;
            const float* src = ent + (tile0 + tau) * 8192 + mr * 256 + ((lane ^ j) << 2);
            float* dst = &buf[nb][tau * 8192 + mr * 256];
            __builtin_amdgcn_global_load_lds((const GLOBAL_AS void*)src,
                                             (LDS_AS void*)dst, 16, 0, 0);
        }
    };

    stage(0, 0);
    __syncthreads();   // drains vmcnt -> buf[0] ready

    int cur = 0;
    #pragma unroll 1
    for (int r = 0; r < 4; ++r) {
        // ---- issue next round's DMA into the other buffer (fire and forget) ----
        if (r < 3) stage(r + 1, cur ^ 1);
        __builtin_amdgcn_sched_barrier(0);

        // ---- MFMA + fused tanh/Ws partial logits (waves 0..6, both tiles) ----
        if (wid < NJ) {
            #pragma unroll
            for (int tau = 0; tau < 2; ++tau) {
                const float4* bf4 = reinterpret_cast<const float4*>(&buf[cur][tau * 8192]);
                const int sm = m & 7;
                f32x16 acc;
                #pragma unroll
                for (int q = 0; q < 16; ++q) acc[q] = 0.f;
                #pragma unroll
                for (int kk = 0; kk < 16; ++kk) {
                    const int s0 = (kk * 4 + hi) ^ sm;      // low-half float4 slot
                    float4 p0 = bf4[m * 64 + s0];
                    float4 p1 = bf4[m * 64 + (s0 ^ 2)];     // high half (= c0+2)
                    bf16x8 fr = { (__bf16)p0.x, (__bf16)p0.y, (__bf16)p0.z, (__bf16)p0.w,
                                  (__bf16)p1.x, (__bf16)p1.y, (__bf16)p1.z, (__bf16)p1.w };
                    acc = __builtin_amdgcn_mfma_f32_32x32x16_bf16(fr, B[kk], acc, 0, 0, 0);
                }
                #pragma unroll
                for (int q = 0; q < 16; ++q) {
                    float v = tanh_fast(acc[q] + ha) * wsa;
                    v += __shfl_xor(v, 1);  v += __shfl_xor(v, 2);  v += __shfl_xor(v, 4);
                    v += __shfl_xor(v, 8);  v += __shfl_xor(v, 16);
                    if (m == 0)
                        partials[tau][wid][(q & 3) + 8 * (q >> 2) + 4 * hi] = v;
                }
            }
        }
        __syncthreads();   // partials ready; drains next-round DMA (covered by compute)

        // ---- epilogue: softmax + weighted sum from swizzled LDS; 4 waves/tile ----
        {
            const int tau = wid >> 2;
            const int q4  = wid & 3;
            const int e0  = lane & 31;
            float lg = 0.f;
            #pragma unroll
            for (int w = 0; w < NJ; ++w) lg += partials[tau][w][e0];
            float mx = lg;
            mx = fmaxf(mx, __shfl_xor(mx, 1));  mx = fmaxf(mx, __shfl_xor(mx, 2));
            mx = fmaxf(mx, __shfl_xor(mx, 4));  mx = fmaxf(mx, __shfl_xor(mx, 8));
            mx = fmaxf(mx, __shfl_xor(mx, 16));
            float ex = __expf(lg - mx);
            float sm_ = ex;
            sm_ += __shfl_xor(sm_, 1);  sm_ += __shfl_xor(sm_, 2);  sm_ += __shfl_xor(sm_, 4);
            sm_ += __shfl_xor(sm_, 8);  sm_ += __shfl_xor(sm_, 16);
            const float wv = ex * __builtin_amdgcn_rcpf(sm_);
            const float* bt = &buf[cur][tau * 8192];
            const int d = q4 * 64 + lane;
            float o = 0.f;
            #pragma unroll
            for (int e = 0; e < NE; ++e) {
                float we = __shfl(wv, e);
                // float col d of row e: slot = (d>>2) ^ (e&7), elem = d&3
                o = fmaf(we, bt[e * 256 + ((((d >> 2) ^ (e & 7)) << 2) | (d & 3))], o);
            }
            out[(size_t)(g * 8 + r * 2 + tau) * 256 + d] = o;
        }
        __syncthreads();   // buf[cur] consumed; safe to be next DMA target
        cur ^= 1;
    }
}

extern "C" void kernel_launch(void* const* d_in, const int* in_sizes, int n_in,
                              void* d_out, int out_size, void* d_ws, size_t ws_size,
                              hipStream_t stream) {
    const float* cxt = (const float*)d_in[0];
    const float* ent = (const float*)d_in[1];
    const float* We  = (const float*)d_in[2];
    const float* Wh  = (const float*)d_in[3];
    const float* Ws  = (const float*)d_in[4];
    float* out = (float*)d_out;

    float*  psum  = (float*)d_ws;                       // 512*512 f32 = 1 MB
    float*  hattw = psum + 512 * DH;                    // 8*224 f32
    __bf16* wef   = (__bf16*)(hattw + NB * DAP);        // 7*16*512 bf16 = 112 KB

    hipLaunchKernelGGL(wef_build, dim3(NJ * 16), dim3(64), 0, stream, We, wef);
    hipLaunchKernelGGL(cmean_partial, dim3(512), dim3(256), 0, stream, cxt, psum);
    hipLaunchKernelGGL(hatt_from_psum, dim3(NB), dim3(256), 0, stream, psum, Wh, hattw);
    hipLaunchKernelGGL(entatt_main, dim3(512), dim3(512), 0, stream,
                       ent, wef, hattw, Ws, out);
}

// Round 18
// 98.528 us; speedup vs baseline: 1.5360x; 1.3077x over previous
//
#include <hip/hip_runtime.h>
#include <math.h>

#define NB 8
#define NS 512
#define NE 32
#define DE 256
#define DH 512
#define DA 200
#define DAP 224   // padded att dim (7 tiles of 32)
#define NJ 7

typedef __bf16 bf16x8 __attribute__((ext_vector_type(8)));
typedef float f32x16 __attribute__((ext_vector_type(16)));

__device__ __forceinline__ float tanh_fast(float x) {
    float e = __expf(x + x);
    return fmaf(-2.f, __builtin_amdgcn_rcpf(e + 1.f), 1.f);
}

// ---- stage 1: partial sums of cxt over s-chunks (512 blocks) ----
__global__ __launch_bounds__(256) void cmean_partial(const float* __restrict__ cxt,
                                                     float* __restrict__ psum) {
    const int g = blockIdx.x;       // b*64 + c
    const int b = g >> 6, c = g & 63;
    const int t = threadIdx.x;
    const float* base = cxt + ((size_t)b * NS + c * 8) * DH;
    float s0 = 0.f, s1 = 0.f;
    #pragma unroll
    for (int s = 0; s < 8; ++s) {
        s0 += base[s * DH + t];
        s1 += base[s * DH + t + 256];
    }
    psum[(size_t)g * DH + t]       = s0;
    psum[(size_t)g * DH + t + 256] = s1;
}

// ---- stage 2: reduce partials -> cmean; hatt[b][a] = cmean @ Wh (zero-padded) ----
__global__ __launch_bounds__(256) void hatt_from_psum(const float* __restrict__ psum,
                                                      const float* __restrict__ Wh,
                                                      float* __restrict__ hattw) {
    const int b = blockIdx.x;
    const int t = threadIdx.x;
    __shared__ float cm[DH];
    float s0 = 0.f, s1 = 0.f;
    for (int c = 0; c < 64; ++c) {
        s0 += psum[((size_t)b * 64 + c) * DH + t];
        s1 += psum[((size_t)b * 64 + c) * DH + t + 256];
    }
    cm[t]       = s0 * (1.f / NS);
    cm[t + 256] = s1 * (1.f / NS);
    __syncthreads();
    if (t < DAP) {
        float acc = 0.f;
        if (t < DA)
            for (int h = 0; h < DH; ++h)
                acc = fmaf(cm[h], Wh[h * DA + t], acc);
        hattw[b * DAP + t] = acc;
    }
}

// ---- stage 3: pack We into bf16 B-fragment layout (zero-padded cols) ----
__global__ __launch_bounds__(64) void wef_build(const float* __restrict__ We,
                                                __bf16* __restrict__ wef) {
    const int f = blockIdx.x;
    const int l = threadIdx.x;
    const int nj = f >> 4, kk = f & 15;
    const int n = nj * 32 + (l & 31);
    bf16x8 v;
    #pragma unroll
    for (int e = 0; e < 8; ++e) {
        int K = kk * 16 + ((l >> 5) << 2) + (e & 3) + 8 * (e >> 2);
        v[e] = (__bf16)((n < DA) ? We[K * DA + n] : 0.f);
    }
    reinterpret_cast<bf16x8*>(wef)[f * 64 + l] = v;
}

// ---- stage 4: PRE-TRANSPOSE ent into bf16 A-fragment order ----
// Rounds 5-17 invariant: wave instructions touching 32 scattered rows read at
// ~1.8 TB/s; contiguous-per-instruction streams are 4-7x faster. This kernel
// is pure streaming: contiguous 32KB read -> LDS (padded rows, 4-way max) ->
// contiguous 16KB fragment write. Frag A[kk] lane(m,hi) = cols
// {kk*16+hi*4+0..3, +8..11} of row m  (same mapping r13 verified).
__global__ __launch_bounds__(256) void entf_build(const float* __restrict__ ent,
                                                  __bf16* __restrict__ entf) {
    const int bs = blockIdx.x;
    const int t  = threadIdx.x;
    __shared__ float L[32 * 260];   // +4 pad per row: banks spread
    const float4* s4 = reinterpret_cast<const float4*>(ent + (size_t)bs * 8192);
    #pragma unroll
    for (int i = 0; i < 8; ++i) {
        float4 v = s4[t + i * 256];            // contiguous across block
        int f4 = t + i * 256;
        int m = f4 >> 6, c4 = f4 & 63;
        *reinterpret_cast<float4*>(&L[m * 260 + c4 * 4]) = v;
    }
    __syncthreads();
    bf16x8* dst = reinterpret_cast<bf16x8*>(entf) + (size_t)bs * 1024;
    #pragma unroll
    for (int q = 0; q < 4; ++q) {
        int idx  = q * 256 + t;                // kk*64 + lane
        int kk   = idx >> 6, lane = idx & 63;
        int m    = lane & 31, hi = lane >> 5;
        const float* p = &L[m * 260 + kk * 16 + hi * 4];
        bf16x8 v = { (__bf16)p[0], (__bf16)p[1], (__bf16)p[2],  (__bf16)p[3],
                     (__bf16)p[8], (__bf16)p[9], (__bf16)p[10], (__bf16)p[11] };
        dst[idx] = v;                          // contiguous across block
    }
}

// ---- main (frag path): r13 structure, A-frags loaded CONTIGUOUSLY ----
// ONE 16-wave block per CU, full wef in LDS, one tile per wave; A-frag loads
// issued AFTER the barrier (r13 lesson: pre-barrier loads serialize the CU).
// vs r13: 16 contiguous 1KB loads replace 32 scattered ones + 256 cvts.
__global__ __launch_bounds__(1024) void entatt_main_frag(const float* __restrict__ ent,
                                                         const __bf16* __restrict__ entf,
                                                         const __bf16* __restrict__ wef,
                                                         const float* __restrict__ hattw,
                                                         const float* __restrict__ Ws,
                                                         float* __restrict__ out) {
    const int t    = threadIdx.x;
    const int lane = t & 63;
    const int wid  = t >> 6;            // 0..15
    const int g    = blockIdx.x;        // 0..255
    const int bs   = g * 16 + wid;      // one tile per wave
    const int b    = g >> 5;            // 32 blocks per batch

    __shared__ __bf16 wef_lds[NJ * 16 * 512];   // 112 KB
    __shared__ float  hatt_lds[DAP];
    __shared__ float  ws_lds[DAP];
    __shared__ float  lg_lds[16][NE];

    // ---- stage full wef -> LDS (coalesced 16B; 7 float4 per thread) ----
    {
        const float4* s4 = reinterpret_cast<const float4*>(wef);
        float4* d4 = reinterpret_cast<float4*>(wef_lds);
        #pragma unroll
        for (int i = 0; i < NJ; ++i) d4[t + i * 1024] = s4[t + i * 1024];
    }
    if (t < DAP) {
        hatt_lds[t] = hattw[b * DAP + t];
        ws_lds[t]   = (t < DA) ? Ws[t] : 0.f;
    }

    __syncthreads();   // only staging traffic drains here

    const int m  = lane & 31;
    const int hi = lane >> 5;

    // ---- A fragments: 16 lane-linear CONTIGUOUS 1KB loads, post-barrier ----
    const bf16x8* ef8 = reinterpret_cast<const bf16x8*>(entf) + (size_t)bs * 1024 + lane;
    bf16x8 A[16];
    #pragma unroll
    for (int kk = 0; kk < 16; ++kk) A[kk] = ef8[kk * 64];

    const bf16x8* w8 = reinterpret_cast<const bf16x8*>(wef_lds);

    float part[16];
    #pragma unroll
    for (int r = 0; r < 16; ++r) part[r] = 0.f;

    #pragma unroll 1
    for (int nj = 0; nj < NJ; ++nj) {
        f32x16 acc;
        #pragma unroll
        for (int r = 0; r < 16; ++r) acc[r] = 0.f;
        #pragma unroll
        for (int kk = 0; kk < 16; ++kk)
            acc = __builtin_amdgcn_mfma_f32_32x32x16_bf16(
                      A[kk], w8[(nj * 16 + kk) * 64 + lane], acc, 0, 0, 0);
        const float ha  = hatt_lds[nj * 32 + m];
        const float wsa = ws_lds[nj * 32 + m];
        #pragma unroll
        for (int r = 0; r < 16; ++r)
            part[r] = fmaf(tanh_fast(acc[r] + ha), wsa, part[r]);
    }

    #pragma unroll
    for (int r = 0; r < 16; ++r) {
        float v = part[r];
        v += __shfl_xor(v, 1);  v += __shfl_xor(v, 2);  v += __shfl_xor(v, 4);
        v += __shfl_xor(v, 8);  v += __shfl_xor(v, 16);
        part[r] = v;
    }
    if (m == 0) {
        #pragma unroll
        for (int r = 0; r < 16; ++r)
            lg_lds[wid][(r & 3) + 8 * (r >> 2) + 4 * hi] = part[r];
    }
    // same-wave LDS RAW: compiler inserts lgkmcnt wait

    // ---- softmax + fp32 weighted sum; eb4 reads contiguous per instruction ----
    float mx = -1e30f;
    #pragma unroll
    for (int e = 0; e < NE; ++e) mx = fmaxf(mx, lg_lds[wid][e]);

    const float4* eb4 = reinterpret_cast<const float4*>(ent + (size_t)bs * (NE * DE));
    float wsum = 0.f;
    float4 o = make_float4(0.f, 0.f, 0.f, 0.f);
    #pragma unroll
    for (int e = 0; e < NE; ++e) {
        float w = __expf(lg_lds[wid][e] - mx);
        wsum += w;
        float4 v = eb4[e * 64 + lane];
        o.x = fmaf(w, v.x, o.x); o.y = fmaf(w, v.y, o.y);
        o.z = fmaf(w, v.z, o.z); o.w = fmaf(w, v.w, o.w);
    }
    const float inv = __builtin_amdgcn_rcpf(wsum);
    float4 res = make_float4(o.x * inv, o.y * inv, o.z * inv, o.w * inv);
    reinterpret_cast<float4*>(out)[(size_t)bs * 64 + lane] = res;
}

// ---- fallback main (r13 exact): direct scattered loads + cvt ----
__global__ __launch_bounds__(1024) void entatt_main_direct(const float* __restrict__ ent,
                                                           const __bf16* __restrict__ wef,
                                                           const float* __restrict__ hattw,
                                                           const float* __restrict__ Ws,
                                                           float* __restrict__ out) {
    const int t    = threadIdx.x;
    const int lane = t & 63;
    const int wid  = t >> 6;
    const int g    = blockIdx.x;
    const int bs   = g * 16 + wid;
    const int b    = g >> 5;

    __shared__ __bf16 wef_lds[NJ * 16 * 512];
    __shared__ float  hatt_lds[DAP];
    __shared__ float  ws_lds[DAP];
    __shared__ float  lg_lds[16][NE];

    {
        const float4* s4 = reinterpret_cast<const float4*>(wef);
        float4* d4 = reinterpret_cast<float4*>(wef_lds);
        #pragma unroll
        for (int i = 0; i < NJ; ++i) d4[t + i * 1024] = s4[t + i * 1024];
    }
    if (t < DAP) {
        hatt_lds[t] = hattw[b * DAP + t];
        ws_lds[t]   = (t < DA) ? Ws[t] : 0.f;
    }
    __syncthreads();

    const int m  = lane & 31;
    const int hi = lane >> 5;
    const float* eb = ent + (size_t)bs * (NE * DE);

    bf16x8 A[16];
    #pragma unroll
    for (int kk = 0; kk < 16; ++kk) {
        const float* p = eb + m * DE + kk * 16 + hi * 4;
        float4 u0 = *reinterpret_cast<const float4*>(p);
        float4 u1 = *reinterpret_cast<const float4*>(p + 8);
        bf16x8 v = { (__bf16)u0.x, (__bf16)u0.y, (__bf16)u0.z, (__bf16)u0.w,
                     (__bf16)u1.x, (__bf16)u1.y, (__bf16)u1.z, (__bf16)u1.w };
        A[kk] = v;
    }

    const bf16x8* w8 = reinterpret_cast<const bf16x8*>(wef_lds);
    float part[16];
    #pragma unroll
    for (int r = 0; r < 16; ++r) part[r] = 0.f;

    #pragma unroll 1
    for (int nj = 0; nj < NJ; ++nj) {
        f32x16 acc;
        #pragma unroll
        for (int r = 0; r < 16; ++r) acc[r] = 0.f;
        #pragma unroll
        for (int kk = 0; kk < 16; ++kk)
            acc = __builtin_amdgcn_mfma_f32_32x32x16_bf16(
                      A[kk], w8[(nj * 16 + kk) * 64 + lane], acc, 0, 0, 0);
        const float ha  = hatt_lds[nj * 32 + m];
        const float wsa = ws_lds[nj * 32 + m];
        #pragma unroll
        for (int r = 0; r < 16; ++r)
            part[r] = fmaf(tanh_fast(acc[r] + ha), wsa, part[r]);
    }

    #pragma unroll
    for (int r = 0; r < 16; ++r) {
        float v = part[r];
        v += __shfl_xor(v, 1);  v += __shfl_xor(v, 2);  v += __shfl_xor(v, 4);
        v += __shfl_xor(v, 8);  v += __shfl_xor(v, 16);
        part[r] = v;
    }
    if (m == 0) {
        #pragma unroll
        for (int r = 0; r < 16; ++r)
            lg_lds[wid][(r & 3) + 8 * (r >> 2) + 4 * hi] = part[r];
    }

    float mx = -1e30f;
    #pragma unroll
    for (int e = 0; e < NE; ++e) mx = fmaxf(mx, lg_lds[wid][e]);

    const float4* eb4 = reinterpret_cast<const float4*>(eb);
    float wsum = 0.f;
    float4 o = make_float4(0.f, 0.f, 0.f, 0.f);
    #pragma unroll
    for (int e = 0; e < NE; ++e) {
        float w = __expf(lg_lds[wid][e] - mx);
        wsum += w;
        float4 v = eb4[e * 64 + lane];
        o.x = fmaf(w, v.x, o.x); o.y = fmaf(w, v.y, o.y);
        o.z = fmaf(w, v.z, o.z); o.w = fmaf(w, v.w, o.w);
    }
    const float inv = __builtin_amdgcn_rcpf(wsum);
    float4 res = make_float4(o.x * inv, o.y * inv, o.z * inv, o.w * inv);
    reinterpret_cast<float4*>(out)[(size_t)bs * 64 + lane] = res;
}

extern "C" void kernel_launch(void* const* d_in, const int* in_sizes, int n_in,
                              void* d_out, int out_size, void* d_ws, size_t ws_size,
                              hipStream_t stream) {
    const float* cxt = (const float*)d_in[0];
    const float* ent = (const float*)d_in[1];
    const float* We  = (const float*)d_in[2];
    const float* Wh  = (const float*)d_in[3];
    const float* Ws  = (const float*)d_in[4];
    float* out = (float*)d_out;

    char* ws = (char*)d_ws;
    float*  psum  = (float*)ws;                          // 1 MB
    float*  hattw = (float*)(ws + 512 * DH * 4);         // 7 KB
    __bf16* wef   = (__bf16*)(ws + 512 * DH * 4 + NB * DAP * 4);   // 112 KB
    const size_t entf_off = 512 * DH * 4 + NB * DAP * 4 + (size_t)NJ * 16 * 512 * 2;
    __bf16* entf  = (__bf16*)(ws + entf_off);            // 64 MB
    const size_t need = entf_off + (size_t)NB * NS * NE * DE * 2;

    hipLaunchKernelGGL(wef_build, dim3(NJ * 16), dim3(64), 0, stream, We, wef);
    hipLaunchKernelGGL(cmean_partial, dim3(512), dim3(256), 0, stream, cxt, psum);
    hipLaunchKernelGGL(hatt_from_psum, dim3(NB), dim3(256), 0, stream, psum, Wh, hattw);

    if (ws_size >= need) {
        hipLaunchKernelGGL(entf_build, dim3(NB * NS), dim3(256), 0, stream, ent, entf);
        hipLaunchKernelGGL(entatt_main_frag, dim3(256), dim3(1024), 0, stream,
                           ent, entf, wef, hattw, Ws, out);
    } else {
        hipLaunchKernelGGL(entatt_main_direct, dim3(256), dim3(1024), 0, stream,
                           ent, wef, hattw, Ws, out);
    }
}